// Round 3
// baseline (273.754 us; speedup 1.0000x reference)
//
#include <hip/hip_runtime.h>

// Problem constants (fixed by the reference):
//   B=128, L=9, K=3, C_IN=C_OUT=256, P=1680 (perms of [0,0,0,1,1,1,2,2,2], lex order)
#define B_DIM 128
#define L_DIM 9
#define K_DIM 3
#define C 256
#define P_TOT 1680
#define R_DIM 27          // L*K rows of Z per batch
#define TILE_P 80
#define TILES 21          // 1680 / 80

// Workspace layout (bytes):
//   [0, 13440)        packed : uint2[P] — 9 row indices (5b each) + dpos
//   [131072, +3.54MB) Z      : float[B*27*256], Z[b][r][o]
#define WS_Z_OFF 131072

typedef float vfloat4 __attribute__((ext_vector_type(4)));  // native vec for nontemporal builtins

__device__ inline float4 add4(float4 a, float4 b) {
    return make_float4(a.x + b.x, a.y + b.y, a.z + b.z, a.w + b.w);
}

// ---------------------------------------------------------------- prep ----
// packed[p].x = rows[0..5] (5 bits each), packed[p].y = rows[6..8] (5 bits)
//             | dpos << 15,   rows[l] = l*3 + idx[p,l],  dpos = first l where
// perm p differs from perm p-1 (0 for p==0).
__global__ void prep_kernel(const float* __restrict__ M,
                            uint2* __restrict__ packed) {
    int p = blockIdx.x * blockDim.x + threadIdx.x;
    if (p >= P_TOT) return;
    unsigned rows[L_DIM];
#pragma unroll
    for (int l = 0; l < L_DIM; ++l) {
        float m1 = M[(1 * P_TOT + p) * L_DIM + l];
        float m2 = M[(2 * P_TOT + p) * L_DIM + l];
        unsigned a = (unsigned)(m1 + 2.0f * m2 + 0.5f);
        rows[l] = (unsigned)(l * K_DIM) + a;
    }
    unsigned d = 0;
    if (p > 0) {
        while (d < L_DIM) {
            float m1 = M[(1 * P_TOT + (p - 1)) * L_DIM + d];
            float m2 = M[(2 * P_TOT + (p - 1)) * L_DIM + d];
            unsigned pr = d * K_DIM + (unsigned)(m1 + 2.0f * m2 + 0.5f);
            if (pr != rows[d]) break;
            ++d;
        }
    }
    unsigned lo = 0, hi = 0;
#pragma unroll
    for (int l = 0; l < 6; ++l) lo |= rows[l] << (5 * l);
#pragma unroll
    for (int l = 6; l < L_DIM; ++l) hi |= rows[l] << (5 * (l - 6));
    hi |= d << 15;
    packed[p] = make_uint2(lo, hi);
}

// ------------------------------------------------------------- z_kernel ----
// Z[b][l*3+a][o] = sum_c x[b,l,c] * W[a,o,c].
// Grid 768 = B*3(a)*2(o-half); 256 threads = 2 c-halves x 128 o's.
// x loads are block-uniform (compiler scalarizes to s_load); W streamed
// float4.  c-halves reduced through LDS -> 3 waves/SIMD occupancy and half
// the per-thread load chain vs the single-pass version.
__global__ __launch_bounds__(256) void z_kernel(const float* __restrict__ x,
                                                const float* __restrict__ W,
                                                float* __restrict__ Z) {
    __shared__ float red[L_DIM * 128];   // 4.5 KB

    int bid = blockIdx.x;
    int b = bid / 6;
    int rem = bid % 6;
    int a = rem >> 1;
    int ohalf = rem & 1;
    int t = threadIdx.x & 127;
    int chalf = threadIdx.x >> 7;
    int o = ohalf * 128 + t;

    const float4* __restrict__ W4 =
        (const float4*)(W + (size_t)(a * C + o) * C) + chalf * 32;
    const float4* __restrict__ X4 =
        (const float4*)(x + (size_t)b * L_DIM * C) + chalf * 32;

    float acc[L_DIM];
#pragma unroll
    for (int l = 0; l < L_DIM; ++l) acc[l] = 0.0f;

#pragma unroll 8
    for (int c4 = 0; c4 < C / 8; ++c4) {
        float4 wv = W4[c4];
#pragma unroll
        for (int l = 0; l < L_DIM; ++l) {
            float4 xv = X4[l * (C / 4) + c4];  // uniform across block -> s_load
            acc[l] += wv.x * xv.x + wv.y * xv.y + wv.z * xv.z + wv.w * xv.w;
        }
    }
    if (chalf) {
#pragma unroll
        for (int l = 0; l < L_DIM; ++l) red[l * 128 + t] = acc[l];
    }
    __syncthreads();
    if (!chalf) {
        float* zb = Z + (size_t)b * R_DIM * C;
#pragma unroll
        for (int l = 0; l < L_DIM; ++l)
            zb[(l * K_DIM + a) * C + o] = acc[l] + red[l * 128 + t];
    }
}

// ------------------------------------------------------------- y_kernel ----
// y[b,p,:] = sum_l Z[b, rows[p,l], :].  One block per (b, tile of 80 p's).
// Z[b] (27KB) in LDS.  Each wave: 20 consecutive p's, running prefix partials
// p0..p8 in registers; only suffix levels >= dpos recomputed (lex-order
// prefix sharing, ~3.1 rows/p).  All 9 row indices come from ONE broadcast
// ds_read_b64 + readfirstlane -> SALU extracts, so the row ds_read_b128s of
// a p are independent and issue back-to-back (no index-load serialization).
__global__ __launch_bounds__(256) void y_kernel(const float* __restrict__ Z,
                                                const uint2* __restrict__ packed,
                                                float* __restrict__ out) {
    __shared__ float Zs[R_DIM * C];      // 27 KB
    __shared__ uint2 pk[TILE_P];         // 640 B

    int bid = blockIdx.x;
    int b = bid / TILES;
    int tile = bid % TILES;
    int base = tile * TILE_P;

    const float4* Zb4 = (const float4*)(Z + (size_t)b * R_DIM * C);
    float4* Zs4 = (float4*)Zs;
    for (int i = threadIdx.x; i < R_DIM * (C / 4); i += 256) Zs4[i] = Zb4[i];
    if (threadIdx.x < TILE_P) pk[threadIdx.x] = packed[base + threadIdx.x];
    __syncthreads();

    int wave = threadIdx.x >> 6;
    int lane = threadIdx.x & 63;
    const float4* zsr = (const float4*)Zs;
    vfloat4* out4 = (vfloat4*)out;

    float4 p0, p1, p2, p3, p4, p5, p6, p7, p8;

    int pl = wave * (TILE_P / 4);
    for (int j = 0; j < TILE_P / 4; ++j, ++pl) {
        uint2 w = pk[pl];                               // broadcast LDS read
        unsigned lo = __builtin_amdgcn_readfirstlane(w.x);
        unsigned hi = __builtin_amdgcn_readfirstlane(w.y);
        // wave-uniform resume depth: 0 for the wave's first p (prev p not ours)
        int k = (j == 0) ? 0 : (int)(hi >> 15);
        switch (k) {
            case 0: p0 = zsr[(lo & 31u) * 64 + lane]; [[fallthrough]];
            case 1: p1 = add4(p0, zsr[((lo >> 5) & 31u) * 64 + lane]); [[fallthrough]];
            case 2: p2 = add4(p1, zsr[((lo >> 10) & 31u) * 64 + lane]); [[fallthrough]];
            case 3: p3 = add4(p2, zsr[((lo >> 15) & 31u) * 64 + lane]); [[fallthrough]];
            case 4: p4 = add4(p3, zsr[((lo >> 20) & 31u) * 64 + lane]); [[fallthrough]];
            case 5: p5 = add4(p4, zsr[((lo >> 25) & 31u) * 64 + lane]); [[fallthrough]];
            case 6: p6 = add4(p5, zsr[(hi & 31u) * 64 + lane]); [[fallthrough]];
            case 7: p7 = add4(p6, zsr[((hi >> 5) & 31u) * 64 + lane]); [[fallthrough]];
            case 8: p8 = add4(p7, zsr[((hi >> 10) & 31u) * 64 + lane]); break;
            default: break;
        }
        // coalesced 1KB/wave nontemporal store (output is write-once streaming)
        int orow = b * P_TOT + base + pl;
        vfloat4 sv = {p8.x, p8.y, p8.z, p8.w};
        __builtin_nontemporal_store(sv, &out4[(size_t)orow * 64 + lane]);
    }
}

// ------------------------------------------------------------------ launch --
extern "C" void kernel_launch(void* const* d_in, const int* in_sizes, int n_in,
                              void* d_out, int out_size, void* d_ws, size_t ws_size,
                              hipStream_t stream) {
    const float* x = (const float*)d_in[0];  // (128, 9, 256)
    const float* W = (const float*)d_in[1];  // (3, 256, 256)
    const float* M = (const float*)d_in[2];  // (3, 1680, 9)
    float* out = (float*)d_out;              // (128, 1680, 256)

    uint2* packed = (uint2*)d_ws;
    float* Z = (float*)((char*)d_ws + WS_Z_OFF);

    prep_kernel<<<(P_TOT + 255) / 256, 256, 0, stream>>>(M, packed);
    z_kernel<<<B_DIM * K_DIM * 2, 256, 0, stream>>>(x, W, Z);
    y_kernel<<<B_DIM * TILES, 256, 0, stream>>>(Z, packed, out);
}

// Round 4
// 262.348 us; speedup vs baseline: 1.0435x; 1.0435x over previous
//
#include <hip/hip_runtime.h>

// Problem constants (fixed by the reference):
//   B=128, L=9, K=3, C_IN=C_OUT=256, P=1680 (perms of [0,0,0,1,1,1,2,2,2], lex order)
#define B_DIM 128
#define L_DIM 9
#define K_DIM 3
#define C 256
#define P_TOT 1680
#define R_DIM 27          // L*K rows of Z per batch
#define HALF_P 840        // p's per fused block (2 blocks per b)

// Workspace layout (bytes):
//   [0, 13440)          packed : uint2[P] — 9 row indices (5b each) + dpos<<15
//   [16384, 16384+768K) Wt     : float[3*256*256], Wt[a][c][o] = W[a][o][c]
#define WS_WT_OFF 16384

typedef float vfloat4 __attribute__((ext_vector_type(4)));  // for nontemporal stores

__device__ inline float4 add4(float4 a, float4 b) {
    return make_float4(a.x + b.x, a.y + b.y, a.z + b.z, a.w + b.w);
}

// --------------------------------------------------------------- setup ----
// blocks 0..6   : packed[p] from one-hot M (idx = M1 + 2*M2), dpos vs perm p-1
// blocks 7..198 : W transpose -> Wt[a][c][o] so the fused kernel's W stream is
//                 lane-coalesced (lanes along o).  1.5 MB total, ~5 us.
__global__ __launch_bounds__(256) void setup_kernel(const float* __restrict__ M,
                                                    const float* __restrict__ W,
                                                    uint2* __restrict__ packed,
                                                    float* __restrict__ Wt) {
    int bid = blockIdx.x;
    int t = threadIdx.x;
    if (bid < 7) {
        int p = bid * 256 + t;
        if (p >= P_TOT) return;
        unsigned rows[L_DIM];
#pragma unroll
        for (int l = 0; l < L_DIM; ++l) {
            float m1 = M[(1 * P_TOT + p) * L_DIM + l];
            float m2 = M[(2 * P_TOT + p) * L_DIM + l];
            unsigned a = (unsigned)(m1 + 2.0f * m2 + 0.5f);
            rows[l] = (unsigned)(l * K_DIM) + a;
        }
        unsigned d = 0;
        if (p > 0) {
            while (d < L_DIM) {
                float m1 = M[(1 * P_TOT + (p - 1)) * L_DIM + d];
                float m2 = M[(2 * P_TOT + (p - 1)) * L_DIM + d];
                unsigned pr = d * K_DIM + (unsigned)(m1 + 2.0f * m2 + 0.5f);
                if (pr != rows[d]) break;
                ++d;
            }
        }
        unsigned lo = 0, hi = 0;
#pragma unroll
        for (int l = 0; l < 6; ++l) lo |= rows[l] << (5 * l);
#pragma unroll
        for (int l = 6; l < L_DIM; ++l) hi |= rows[l] << (5 * (l - 6));
        hi |= d << 15;
        packed[p] = make_uint2(lo, hi);
    } else {
        int tb = bid - 7;  // 0..191, each does 4 (a,c) rows of 256 o's
#pragma unroll
        for (int i = 0; i < 4; ++i) {
            int rowid = tb * 4 + i;          // 0..767
            int a = rowid >> 8;
            int c = rowid & 255;
            Wt[(a * C + c) * C + t] = W[(a * C + t) * C + c];
        }
    }
}

// --------------------------------------------------------------- fused ----
// One block per (b, half of the p range).  1024 threads = 16 waves.
// Phase A: Z[b][l*3+a][o] = sum_c x[b,l,c] * Wt[a][c][o] straight into LDS.
//   Threads (a = slot 0..2, o = t&255); Wt loads lane-coalesced (256B/instr);
//   x values are wave-uniform LDS broadcasts (ds_read_b128, no conflicts).
//   slot 3 idles (~6 us phase, 2x redundant z-compute across halves: free,
//   total z work is only 0.9 GFLOP).
// Phase B: per wave 52-53 consecutive p's; running prefix partials p0..p8 in
//   registers, resume at dpos (lex-order prefix sharing ~3.1 rows/p); all 9
//   row indices from one LDS uint2 -> SALU extracts -> independent
//   ds_read_b128s; 1KB/wave nontemporal coalesced stores.
__global__ __launch_bounds__(1024) void fused_kernel(const float* __restrict__ x,
                                                     const uint2* __restrict__ packed,
                                                     const float* __restrict__ Wt,
                                                     float* __restrict__ out) {
    __shared__ float xs[L_DIM * C];      // 9 KB
    __shared__ float Zs[R_DIM * C];      // 27 KB
    __shared__ uint2 pk[HALF_P];         // 6.72 KB

    int bid = blockIdx.x;
    int b = bid >> 1;
    int pstart = (bid & 1) * HALF_P;
    int t = threadIdx.x;

    // stage x[b] (9 KB) and this block's packed indices
    if (t < L_DIM * C / 4) ((float4*)xs)[t] = ((const float4*)(x + (size_t)b * L_DIM * C))[t];
    if (t < HALF_P) pk[t] = packed[pstart + t];
    __syncthreads();

    // ---- Phase A: Z[b] into LDS ----
    int o = t & 255;
    int slot = t >> 8;
    if (slot < K_DIM) {
        const float* __restrict__ wp = Wt + (size_t)slot * C * C + o;
        float acc[L_DIM];
#pragma unroll
        for (int l = 0; l < L_DIM; ++l) acc[l] = 0.0f;
#pragma unroll 2
        for (int c4 = 0; c4 < C / 4; ++c4) {
            float w0 = wp[(4 * c4 + 0) * C];
            float w1 = wp[(4 * c4 + 1) * C];
            float w2 = wp[(4 * c4 + 2) * C];
            float w3 = wp[(4 * c4 + 3) * C];
#pragma unroll
            for (int l = 0; l < L_DIM; ++l) {
                float4 xv = ((const float4*)xs)[l * (C / 4) + c4];  // uniform broadcast
                acc[l] += xv.x * w0 + xv.y * w1 + xv.z * w2 + xv.w * w3;
            }
        }
#pragma unroll
        for (int l = 0; l < L_DIM; ++l) Zs[(l * K_DIM + slot) * C + o] = acc[l];
    }
    __syncthreads();

    // ---- Phase B: stream the p's ----
    int wave = t >> 6;
    int lane = t & 63;
    const float4* zsr = (const float4*)Zs;
    vfloat4* out4 = (vfloat4*)out;

    int pb = (HALF_P * wave) >> 4;
    int pe = (HALF_P * (wave + 1)) >> 4;

    float4 p0, p1, p2, p3, p4, p5, p6, p7, p8;

    for (int pl = pb; pl < pe; ++pl) {
        uint2 w = pk[pl];                               // broadcast LDS read
        unsigned lo = __builtin_amdgcn_readfirstlane(w.x);
        unsigned hi = __builtin_amdgcn_readfirstlane(w.y);
        // wave-uniform resume depth: 0 for the wave's first p (prev p not ours)
        int k = (pl == pb) ? 0 : (int)(hi >> 15);
        switch (k) {
            case 0: p0 = zsr[(lo & 31u) * 64 + lane]; [[fallthrough]];
            case 1: p1 = add4(p0, zsr[((lo >> 5) & 31u) * 64 + lane]); [[fallthrough]];
            case 2: p2 = add4(p1, zsr[((lo >> 10) & 31u) * 64 + lane]); [[fallthrough]];
            case 3: p3 = add4(p2, zsr[((lo >> 15) & 31u) * 64 + lane]); [[fallthrough]];
            case 4: p4 = add4(p3, zsr[((lo >> 20) & 31u) * 64 + lane]); [[fallthrough]];
            case 5: p5 = add4(p4, zsr[((lo >> 25) & 31u) * 64 + lane]); [[fallthrough]];
            case 6: p6 = add4(p5, zsr[(hi & 31u) * 64 + lane]); [[fallthrough]];
            case 7: p7 = add4(p6, zsr[((hi >> 5) & 31u) * 64 + lane]); [[fallthrough]];
            case 8: p8 = add4(p7, zsr[((hi >> 10) & 31u) * 64 + lane]); break;
            default: break;
        }
        // coalesced 1KB/wave nontemporal store (write-once streaming output)
        size_t orow = (size_t)(b * P_TOT + pstart + pl);
        vfloat4 sv = {p8.x, p8.y, p8.z, p8.w};
        __builtin_nontemporal_store(sv, &out4[orow * 64 + lane]);
    }
}

// ------------------------------------------------------------------ launch --
extern "C" void kernel_launch(void* const* d_in, const int* in_sizes, int n_in,
                              void* d_out, int out_size, void* d_ws, size_t ws_size,
                              hipStream_t stream) {
    const float* x = (const float*)d_in[0];  // (128, 9, 256)
    const float* W = (const float*)d_in[1];  // (3, 256, 256)
    const float* M = (const float*)d_in[2];  // (3, 1680, 9)
    float* out = (float*)d_out;              // (128, 1680, 256)

    uint2* packed = (uint2*)d_ws;
    float* Wt = (float*)((char*)d_ws + WS_WT_OFF);

    setup_kernel<<<199, 256, 0, stream>>>(M, W, packed, Wt);
    fused_kernel<<<B_DIM * 2, 1024, 0, stream>>>(x, packed, Wt, out);
}